// Round 17
// baseline (491.126 us; speedup 1.0000x reference)
//
#include <hip/hip_runtime.h>
#include <math.h>

// GCN 2-layer, N=500k, E=16M, F 5->5->8.
// R17: R16 + fused per-layer aggregation. Phase split moved INSIDE the wave:
//   lanes 0-7 walk phase-0 list, lanes 8-15 phase-1 list, ONE 16-wide
//   butterfly, one epilogue. Removes per layer: 1 butterfly/node, acc4/acc1
//   round-trip (40 MB), 1 launch, duplicate ptr loads. (R16 showed aggs are
//   VALU/overhead-bound, not BW-bound, so the L2-hit-rate drop is accepted.)
// Fallback: R1 atomic-scatter path if ws/shape limits exceeded.

#define FIN 5
#define FHID 5
#define FOUT 8
#define RB 256        // nodes per bucket
#define EPA 32768     // edges per level-A block (128 KB staging)
#define NBUCK_MAX 2048
#define OCAP 10240    // passC staging cap (= 20 regs x 512 threads)

typedef _Float16 half8 __attribute__((ext_vector_type(8)));
typedef int int4v __attribute__((ext_vector_type(4)));
typedef float fl4 __attribute__((ext_vector_type(4)));

// ---------------- scans ----------------

__global__ void k_scan1(const int* __restrict__ t, int* __restrict__ scn,
                        int* __restrict__ partial, int n) {
    __shared__ int sh[256];
    int tx = threadIdx.x;
    int i = blockIdx.x * 256 + tx;
    int v = (i < n) ? t[i] : 0;
    sh[tx] = v;
    __syncthreads();
    for (int off = 1; off < 256; off <<= 1) {
        int add = (tx >= off) ? sh[tx - off] : 0;
        __syncthreads();
        sh[tx] += add;
        __syncthreads();
    }
    if (i < n) scn[i] = sh[tx] - v;
    if (tx == 255) partial[blockIdx.x] = sh[255];
}

__global__ void k_scan2(int* __restrict__ partial, int nb) {
    __shared__ int sh[256];
    __shared__ int carry;
    int tx = threadIdx.x;
    if (tx == 0) carry = 0;
    __syncthreads();
    for (int base = 0; base < nb; base += 256) {
        int i = base + tx;
        int v = (i < nb) ? partial[i] : 0;
        int c0 = carry;
        sh[tx] = v;
        __syncthreads();
        for (int off = 1; off < 256; off <<= 1) {
            int add = (tx >= off) ? sh[tx - off] : 0;
            __syncthreads();
            sh[tx] += add;
            __syncthreads();
        }
        if (i < nb) partial[i] = c0 + sh[tx] - v;
        __syncthreads();
        if (tx == 0) carry = c0 + sh[255];
        __syncthreads();
    }
}

// ---------------- binning ----------------

__global__ void k_histA(const int* __restrict__ dst, int* __restrict__ cnt,
                        int e, int nbuck, int nblkA) {
    __shared__ int hist[NBUCK_MAX];
    int tx = threadIdx.x, blk = blockIdx.x;
    for (int b = tx; b < nbuck; b += 1024) hist[b] = 0;
    __syncthreads();
    size_t base = (size_t)blk * EPA;
    const int4v* dst4 = (const int4v*)dst;
    for (int k = 0; k < EPA / 4096; ++k) {
        size_t e4 = base / 4 + (size_t)k * 1024 + tx;
        size_t i = e4 * 4;
        if (i + 3 < (size_t)e) {
            int4v d4 = __builtin_nontemporal_load(&dst4[e4]);
#pragma unroll
            for (int j = 0; j < 4; ++j) atomicAdd(&hist[d4[j] >> 8], 1);
        } else {
            for (int j = 0; j < 4; ++j) {
                size_t ii = i + j;
                if (ii < (size_t)e) atomicAdd(&hist[dst[ii] >> 8], 1);
            }
        }
    }
    __syncthreads();
    for (int b = tx; b < nbuck; b += 1024) cnt[(size_t)b * nblkA + blk] = hist[b];
}

// LDS-staged scatter: local hist LOADED from cnt (histA already computed it),
// scan -> stage sorted-by-bucket into LDS -> coalesced run flush.
__global__ void k_scatterA(const int* __restrict__ src, const int* __restrict__ dst,
                           const int* __restrict__ cnt,
                           const int* __restrict__ scn, const int* __restrict__ part,
                           unsigned int* __restrict__ binnedA,
                           int e, int nbuck, int nblkA) {
    __shared__ int lstart[NBUCK_MAX];          // local counts -> exclusive scan
    __shared__ int cur[NBUCK_MAX];
    __shared__ int gbase[NBUCK_MAX];
    __shared__ unsigned int staged[EPA];       // 128 KB
    int tx = threadIdx.x, blk = blockIdx.x;
    for (int b = tx; b < NBUCK_MAX; b += 1024) {
        if (b < nbuck) {
            size_t idx = (size_t)b * nblkA + blk;
            lstart[b] = cnt[idx];
            gbase[b] = scn[idx] + part[idx >> 8];
        } else {
            lstart[b] = 0;
        }
    }
    __syncthreads();
    // in-place inclusive scan of lstart[2048], 2 elems/thread
    int j0 = tx, j1 = tx + 1024;
    int c0 = lstart[j0], c1 = lstart[j1];
    for (int off = 1; off < NBUCK_MAX; off <<= 1) {
        int a0 = (j0 >= off) ? lstart[j0 - off] : 0;
        int a1 = (j1 >= off) ? lstart[j1 - off] : 0;
        __syncthreads();
        lstart[j0] += a0; lstart[j1] += a1;
        __syncthreads();
    }
    int e0 = lstart[j0] - c0, e1 = lstart[j1] - c1;
    __syncthreads();
    lstart[j0] = e0; lstart[j1] = e1;
    cur[j0] = e0;    cur[j1] = e1;
    __syncthreads();
    // stage sorted-by-bucket into LDS (scattered LDS writes ~free)
    size_t base = (size_t)blk * EPA;
    const int4v* dst4 = (const int4v*)dst;
    const int4v* src4 = (const int4v*)src;
    for (int k = 0; k < EPA / 4096; ++k) {
        size_t e4 = base / 4 + (size_t)k * 1024 + tx;
        size_t i = e4 * 4;
        if (i + 3 < (size_t)e) {
            int4v d4 = __builtin_nontemporal_load(&dst4[e4]);
            int4v s4 = __builtin_nontemporal_load(&src4[e4]);
#pragma unroll
            for (int j = 0; j < 4; ++j) {
                int d = d4[j];
                int pos = atomicAdd(&cur[d >> 8], 1);
                staged[pos] = ((unsigned int)(d & (RB - 1)) << 19) | (unsigned int)s4[j];
            }
        } else {
            for (int j = 0; j < 4; ++j) {
                size_t ii = i + j;
                if (ii < (size_t)e) {
                    int d = dst[ii];
                    int pos = atomicAdd(&cur[d >> 8], 1);
                    staged[pos] = ((unsigned int)(d & (RB - 1)) << 19) | (unsigned int)src[ii];
                }
            }
        }
    }
    __syncthreads();
    // flush: 16 lanes per bucket-run -> contiguous global writes
    int grp = tx >> 4, lane = tx & 15;
    for (int b = grp; b < nbuck; b += 64) {
        int ls = lstart[b];
        int le = (b + 1 < NBUCK_MAX) ? lstart[b + 1] : 0;
        int len = le - ls;
        int gb = gbase[b];
        for (int k = lane; k < len; k += 16)
            binnedA[gb + k] = staged[ls + k];
    }
}

// ---------------- passC: PHASE-MAJOR 512-bin sort + p0ptr/p1ptr + g1 ----------------
// key = (phase<<8)|dl : bucket segment = [phase0 by node | phase1 by node].
// Register-staged: bucket edges (<= OCAP = 20*512) in 20 static VGPRs.

__global__ void k_passC(const unsigned int* __restrict__ binnedA,
                        const int* __restrict__ scn, const int* __restrict__ part,
                        const float* __restrict__ x,
                        half8* __restrict__ g1, unsigned int* __restrict__ binned3,
                        int* __restrict__ p0ptr, int* __restrict__ p1ptr,
                        int n, int e, int nbuck, int nblkA, unsigned int half) {
    __shared__ int hist[2 * RB];       // 512 bins: (phase<<8)|dl
    __shared__ int scanbuf[2 * RB];
    __shared__ int cur[2 * RB];
    __shared__ unsigned int obuf[OCAP];   // 40 KB
    int tx = threadIdx.x, b = blockIdx.x;  // blockDim 512
    hist[tx] = 0;
    __syncthreads();
    size_t i0 = (size_t)b * nblkA;
    int start = scn[i0] + part[i0 >> 8];
    int end;
    if (b + 1 < nbuck) {
        size_t i1 = (size_t)(b + 1) * nblkA;
        end = scn[i1] + part[i1 >> 8];
    } else {
        end = e;
    }
    int len = end - start;
    bool stage = (len <= OCAP);
    unsigned int r[20];
    if (stage) {
#pragma unroll
        for (int k = 0; k < 20; ++k) {
            int i = start + k * 512 + tx;
            if (i < end) {
                unsigned int p = binnedA[i];
                r[k] = p;
                int key = ((p & 0x7FFFFu) >= half ? 256 : 0) | (int)(p >> 19);
                atomicAdd(&hist[key], 1);
            }
        }
    } else {
        for (int i = start + tx; i < end; i += 512) {
            unsigned int p = binnedA[i];
            int key = ((p & 0x7FFFFu) >= half ? 256 : 0) | (int)(p >> 19);
            atomicAdd(&hist[key], 1);
        }
    }
    __syncthreads();
    int v = hist[tx];
    scanbuf[tx] = v;
    __syncthreads();
    for (int off = 1; off < 2 * RB; off <<= 1) {
        int add = (tx >= off) ? scanbuf[tx - off] : 0;
        __syncthreads();
        scanbuf[tx] += add;
        __syncthreads();
    }
    int excl = scanbuf[tx] - v;
    cur[tx] = excl;
    if (tx < 256) p0ptr[(size_t)b * RB + tx] = start + excl;
    else          p1ptr[(size_t)b * RB + (tx - 256)] = start + excl;
    if (tx < RB) {
        int node = b * RB + tx;
        if (node < n) {
            int deg = hist[tx] + hist[256 + tx];
            float d = rsqrtf((float)(deg + 1));  // +1 self-loop
            const float* xp = x + (size_t)node * FIN;
            half8 row = {};
#pragma unroll
            for (int f = 0; f < FIN; ++f) row[f] = (_Float16)(xp[f] * d);
            row[5] = (_Float16)d;                // dinv folded into slot 5
            g1[node] = row;
        }
    }
    if (b == nbuck - 1 && tx == 0) p0ptr[(size_t)nbuck * RB] = end;  // global sentinel
    __syncthreads();
    if (stage) {
#pragma unroll
        for (int k = 0; k < 20; ++k) {
            int i = start + k * 512 + tx;
            if (i < end) {
                unsigned int p = r[k];
                int key = ((p & 0x7FFFFu) >= half ? 256 : 0) | (int)(p >> 19);
                int pos = atomicAdd(&cur[key], 1);
                obuf[pos] = p & 0x7FFFFu;
            }
        }
        __syncthreads();
        for (int j = tx; j < len; j += 512)
            binned3[start + j] = obuf[j];
    } else {
        for (int i = start + tx; i < end; i += 512) {
            unsigned int p = binnedA[i];
            int key = ((p & 0x7FFFFu) >= half ? 256 : 0) | (int)(p >> 19);
            int pos = atomicAdd(&cur[key], 1);
            binned3[start + pos] = p & 0x7FFFFu;
        }
    }
}

// ---------------- fused aggregation: 16 lanes/node, dual-phase in-wave ----------------
// lanes 0-7 walk phase-0 list, lanes 8-15 walk phase-1 list; one butterfly.
// phase-0 range: [p0[node], dl==255 ? p1[bucket_first] : p0[node+1])
// phase-1 range: [p1[node], dl==255 ? p0[bucket_first+RB] : p1[node+1])

__device__ __forceinline__ void fused_ranges(const int* __restrict__ p0,
                                             const int* __restrict__ p1,
                                             int node, int lane, int& st, int& en) {
    int dl = node & (RB - 1);
    int q0  = p0[node];
    int q0e = (dl == RB - 1) ? p1[node & ~(RB - 1)] : p0[node + 1];
    int q1  = p1[node];
    int q1e = (dl == RB - 1) ? p0[(node & ~(RB - 1)) + RB] : p1[node + 1];
    bool ph0 = (lane < 8);
    st = (ph0 ? q0 : q1) + (lane & 7);
    en = ph0 ? q0e : q1e;
}

// layer 1: fused both-phase gather + W1+relu epilogue -> g2
__global__ void k_fused1(const unsigned int* __restrict__ ed,
                         const int* __restrict__ p0, const int* __restrict__ p1,
                         const half8* __restrict__ g1,
                         const float* __restrict__ W1, const float* __restrict__ b1,
                         half8* __restrict__ g2, int n) {
    int tid = blockIdx.x * blockDim.x + threadIdx.x;
    int node = tid >> 4;
    int lane = tid & 15;
    if (node >= n) return;
    int st, en;
    fused_ranges(p0, p1, node, lane, st, en);
    float a0 = 0, a1 = 0, a2 = 0, a3 = 0, a4 = 0;
    for (int k = st; k < en; k += 8) {
        unsigned int s = __builtin_nontemporal_load(&ed[k]);
        half8 hv = g1[s];
        a0 += (float)hv[0]; a1 += (float)hv[1]; a2 += (float)hv[2];
        a3 += (float)hv[3]; a4 += (float)hv[4];
    }
#pragma unroll
    for (int off = 1; off < 16; off <<= 1) {
        a0 += __shfl_xor(a0, off, 16);
        a1 += __shfl_xor(a1, off, 16);
        a2 += __shfl_xor(a2, off, 16);
        a3 += __shfl_xor(a3, off, 16);
        a4 += __shfl_xor(a4, off, 16);
    }
    if (lane == 0) {
        half8 gi = g1[node];
        float d = (float)gi[5];
        float v[FIN];
        v[0] = (a0 + (float)gi[0]) * d;
        v[1] = (a1 + (float)gi[1]) * d;
        v[2] = (a2 + (float)gi[2]) * d;
        v[3] = (a3 + (float)gi[3]) * d;
        v[4] = (a4 + (float)gi[4]) * d;
        half8 go = {};
#pragma unroll
        for (int j = 0; j < FHID; ++j) {
            float s = b1[j];
#pragma unroll
            for (int k = 0; k < FIN; ++k) s = fmaf(v[k], W1[k * FHID + j], s);
            go[j] = (_Float16)(fmaxf(s, 0.0f) * d);  // relu, pre-scaled
        }
        go[5] = gi[5];
        g2[node] = go;
    }
}

// layer 2: fused both-phase gather + parallel softmax epilogue -> out
__global__ void k_fused2(const unsigned int* __restrict__ ed,
                         const int* __restrict__ p0, const int* __restrict__ p1,
                         const half8* __restrict__ g2,
                         const float* __restrict__ W2, const float* __restrict__ b2,
                         float* __restrict__ out, int n) {
    int tid = blockIdx.x * blockDim.x + threadIdx.x;
    int node = tid >> 4;
    int lane = tid & 15;
    if (node >= n) return;
    int st, en;
    fused_ranges(p0, p1, node, lane, st, en);
    float a0 = 0, a1 = 0, a2 = 0, a3 = 0, a4 = 0;
    for (int k = st; k < en; k += 8) {
        unsigned int s = __builtin_nontemporal_load(&ed[k]);
        half8 hv = g2[s];
        a0 += (float)hv[0]; a1 += (float)hv[1]; a2 += (float)hv[2];
        a3 += (float)hv[3]; a4 += (float)hv[4];
    }
    // butterfly: ALL 16 lanes end with the full sums
#pragma unroll
    for (int off = 1; off < 16; off <<= 1) {
        a0 += __shfl_xor(a0, off, 16);
        a1 += __shfl_xor(a1, off, 16);
        a2 += __shfl_xor(a2, off, 16);
        a3 += __shfl_xor(a3, off, 16);
        a4 += __shfl_xor(a4, off, 16);
    }
    half8 gi = g2[node];
    float d = (float)gi[5];
    float v[FHID];
    v[0] = (a0 + (float)gi[0]) * d;
    v[1] = (a1 + (float)gi[1]) * d;
    v[2] = (a2 + (float)gi[2]) * d;
    v[3] = (a3 + (float)gi[3]) * d;
    v[4] = (a4 + (float)gi[4]) * d;
    int j = lane & 7;                      // lane j owns output j (both halves compute)
    float oj = b2[j];
#pragma unroll
    for (int k = 0; k < FHID; ++k) oj = fmaf(v[k], W2[k * FOUT + j], oj);
    float mx = oj;
#pragma unroll
    for (int off = 1; off < 8; off <<= 1) mx = fmaxf(mx, __shfl_xor(mx, off, 8));
    float ex = expf(oj - mx);
    float ss = ex;
#pragma unroll
    for (int off = 1; off < 8; off <<= 1) ss += __shfl_xor(ss, off, 8);
    if (lane < 8) out[(size_t)node * FOUT + j] = oj - mx - logf(ss);  // coalesced
}

// ---------------- fallback (R1 atomic path) ----------------

__global__ void f_init_deg(float* __restrict__ deg, int n) {
    int i = blockIdx.x * blockDim.x + threadIdx.x;
    if (i < n) deg[i] = 1.0f;
}
__global__ void f_count_deg(const int* __restrict__ dst, float* __restrict__ deg, int e) {
    int i = blockIdx.x * blockDim.x + threadIdx.x;
    if (i < e) atomicAdd(&deg[dst[i]], 1.0f);
}
__global__ void f_finish_deg_g1(const float* __restrict__ x, float* __restrict__ dinv,
                                float* __restrict__ g1, int n) {
    int i = blockIdx.x * blockDim.x + threadIdx.x;
    if (i >= n) return;
    float d = rsqrtf(dinv[i]);
    dinv[i] = d;
#pragma unroll
    for (int f = 0; f < FIN; ++f) g1[(size_t)i * FIN + f] = x[(size_t)i * FIN + f] * d;
}
__global__ void f_scatter5(const int* __restrict__ src, const int* __restrict__ dst,
                           const float* __restrict__ g, float* __restrict__ acc, int e) {
    int i = blockIdx.x * blockDim.x + threadIdx.x;
    if (i >= e) return;
    int s = src[i], d = dst[i];
    float* a = acc + (size_t)d * 5;
    const float* gp = g + (size_t)s * 5;
    atomicAdd(a + 0, gp[0]);
    atomicAdd(a + 1, gp[1]);
    atomicAdd(a + 2, gp[2]);
    atomicAdd(a + 3, gp[3]);
    atomicAdd(a + 4, gp[4]);
}
__global__ void f_update1(const float* __restrict__ dinv, float* __restrict__ g,
                          float* __restrict__ acc, const float* __restrict__ W1,
                          const float* __restrict__ b1, int n) {
    int i = blockIdx.x * blockDim.x + threadIdx.x;
    if (i >= n) return;
    float d = dinv[i];
    float v[FIN];
#pragma unroll
    for (int f = 0; f < FIN; ++f) {
        size_t idx = (size_t)i * FIN + f;
        v[f] = (acc[idx] + g[idx]) * d;
        acc[idx] = 0.0f;
    }
#pragma unroll
    for (int j = 0; j < FHID; ++j) {
        float s = b1[j];
#pragma unroll
        for (int k = 0; k < FIN; ++k) s += v[k] * W1[k * FHID + j];
        g[(size_t)i * FHID + j] = fmaxf(s, 0.0f) * d;
    }
}
__global__ void f_update2(const float* __restrict__ dinv, const float* __restrict__ g,
                          const float* __restrict__ acc, const float* __restrict__ W2,
                          const float* __restrict__ b2, float* __restrict__ out, int n) {
    int i = blockIdx.x * blockDim.x + threadIdx.x;
    if (i >= n) return;
    float d = dinv[i];
    float v[FHID];
#pragma unroll
    for (int f = 0; f < FHID; ++f) v[f] = (acc[(size_t)i * FHID + f] + g[(size_t)i * FHID + f]) * d;
    float o[FOUT];
    float m = -1e30f;
#pragma unroll
    for (int j = 0; j < FOUT; ++j) {
        float s = b2[j];
#pragma unroll
        for (int k = 0; k < FHID; ++k) s += v[k] * W2[k * FOUT + j];
        o[j] = s;
        m = fmaxf(m, s);
    }
    float ssum = 0.0f;
#pragma unroll
    for (int j = 0; j < FOUT; ++j) ssum += expf(o[j] - m);
    float lse = m + logf(ssum);
#pragma unroll
    for (int j = 0; j < FOUT; ++j) out[(size_t)i * FOUT + j] = o[j] - lse;
}

// ---------------- launcher ----------------

extern "C" void kernel_launch(void* const* d_in, const int* in_sizes, int n_in,
                              void* d_out, int out_size, void* d_ws, size_t ws_size,
                              hipStream_t stream) {
    const float* x  = (const float*)d_in[0];
    const int*   ei = (const int*)d_in[1];
    const float* W1 = (const float*)d_in[2];
    const float* b1 = (const float*)d_in[3];
    const float* W2 = (const float*)d_in[4];
    const float* b2 = (const float*)d_in[5];

    const int n = in_sizes[0] / FIN;   // 500,000
    const int e = in_sizes[1] / 2;     // 16,000,000
    const int* src = ei;
    const int* dst = ei + e;

    const int nbuck = (n + RB - 1) / RB;          // 1954
    const int nblkA = (e + EPA - 1) / EPA;        // 489
    const size_t m = (size_t)nbuck * nblkA;       // ~955k
    const int nsb = (int)((m + 255) / 256);

    size_t off = 0;
    auto al = [&](size_t bytes) { size_t o = off; off = (off + bytes + 15) & ~(size_t)15; return o; };
    int*          cnt     = (int*)((char*)d_ws + al(m * 4));
    int*          scn     = (int*)((char*)d_ws + al(m * 4));
    int*          part    = (int*)((char*)d_ws + al((size_t)nsb * 4));
    int*          p0ptr   = (int*)((char*)d_ws + al(((size_t)nbuck * RB + 1) * 4));
    int*          p1ptr   = (int*)((char*)d_ws + al((size_t)nbuck * RB * 4));
    half8*        g1      = (half8*)((char*)d_ws + al((size_t)n * 16));
    unsigned int* binnedA = (unsigned int*)((char*)d_ws + al((size_t)e * 4));
    unsigned int* binned3 = (unsigned int*)((char*)d_ws + al((size_t)e * 4));
    // binnedA (64 MB) dead after passC -- reuse its first 8 MB for g2:
    half8*        g2      = (half8*)binnedA;
    const size_t need = off;

    if (ws_size >= need && n <= 524288 && n >= 1 && (e & 3) == 0 && nbuck <= NBUCK_MAX &&
        (size_t)e * 4 >= (size_t)n * 16) {
        const unsigned int half = (unsigned int)(n >> 1);
        k_histA<<<nblkA, 1024, 0, stream>>>(dst, cnt, e, nbuck, nblkA);
        k_scan1<<<nsb, 256, 0, stream>>>(cnt, scn, part, (int)m);
        k_scan2<<<1, 256, 0, stream>>>(part, nsb);
        k_scatterA<<<nblkA, 1024, 0, stream>>>(src, dst, cnt, scn, part, binnedA, e, nbuck, nblkA);
        k_passC<<<nbuck, 512, 0, stream>>>(binnedA, scn, part, x, g1, binned3, p0ptr, p1ptr,
                                           n, e, nbuck, nblkA, half);
        const int ga = (int)(((size_t)n * 16 + 511) / 512);
        k_fused1<<<ga, 512, 0, stream>>>(binned3, p0ptr, p1ptr, g1, W1, b1, g2, n);
        k_fused2<<<ga, 512, 0, stream>>>(binned3, p0ptr, p1ptr, g2, W2, b2, (float*)d_out, n);
        return;
    }

    // R1 fallback (22 MB ws)
    const int B = 256;
    const int gn = (n + B - 1) / B;
    const int ge = (e + B - 1) / B;
    float* fdinv = (float*)d_ws;
    float* fg    = fdinv + n;
    float* facc  = fg + (size_t)5 * n;
    hipMemsetAsync(facc, 0, (size_t)5 * n * sizeof(float), stream);
    f_init_deg<<<gn, B, 0, stream>>>(fdinv, n);
    f_count_deg<<<ge, B, 0, stream>>>(dst, fdinv, e);
    f_finish_deg_g1<<<gn, B, 0, stream>>>(x, fdinv, fg, n);
    f_scatter5<<<ge, B, 0, stream>>>(src, dst, fg, facc, e);
    f_update1<<<gn, B, 0, stream>>>(fdinv, fg, facc, W1, b1, n);
    f_scatter5<<<ge, B, 0, stream>>>(src, dst, fg, facc, e);
    f_update2<<<gn, B, 0, stream>>>(fdinv, fg, facc, W2, b2, (float*)d_out, n);
}

// Round 18
// 435.643 us; speedup vs baseline: 1.1274x; 1.1274x over previous
//
#include <hip/hip_runtime.h>
#include <math.h>

// GCN 2-layer, N=500k, E=16M, F 5->5->8.
// R18: R16 structure restored (phase-split agg ACROSS kernel launches -- R17
//   proved in-wave fusion destroys L2 temporal locality, FETCH 86->597 MB).
//   New: packed-f16 accumulation in all agg gather loops + packed butterfly
//   (4 pk_add/edge vs 10 cvt+add; 24-inst reduce vs 40), f32 convert once in
//   epilogue. Predicted absmax <= 0.035 (threshold 0.0456).
// Fallback: R1 atomic-scatter path if ws/shape limits exceeded.

#define FIN 5
#define FHID 5
#define FOUT 8
#define RB 256        // nodes per bucket
#define EPA 32768     // edges per level-A block (128 KB staging)
#define NBUCK_MAX 2048
#define OCAP 10240    // passC staging cap (= 20 regs x 512 threads)

typedef _Float16 half8 __attribute__((ext_vector_type(8)));
typedef int int4v __attribute__((ext_vector_type(4)));
typedef float fl4 __attribute__((ext_vector_type(4)));

// packed butterfly over width-16 groups: sums half8 accumulators (slots 0-4
// meaningful) across lanes; all lanes end with the full sum.
__device__ __forceinline__ half8 bfly16_h8(half8 a) {
    int4v w = *(int4v*)&a;
#pragma unroll
    for (int off = 1; off < 16; off <<= 1) {
        int4v t;
        t.x = __shfl_xor(w.x, off, 16);
        t.y = __shfl_xor(w.y, off, 16);
        t.z = __shfl_xor(w.z, off, 16);
        t.w = 0;
        half8 o = *(half8*)&t;
        half8 c = *(half8*)&w;
        c += o;                      // 4x v_pk_add_f16
        w = *(int4v*)&c;
    }
    return *(half8*)&w;
}

// ---------------- scans ----------------

__global__ void k_scan1(const int* __restrict__ t, int* __restrict__ scn,
                        int* __restrict__ partial, int n) {
    __shared__ int sh[256];
    int tx = threadIdx.x;
    int i = blockIdx.x * 256 + tx;
    int v = (i < n) ? t[i] : 0;
    sh[tx] = v;
    __syncthreads();
    for (int off = 1; off < 256; off <<= 1) {
        int add = (tx >= off) ? sh[tx - off] : 0;
        __syncthreads();
        sh[tx] += add;
        __syncthreads();
    }
    if (i < n) scn[i] = sh[tx] - v;
    if (tx == 255) partial[blockIdx.x] = sh[255];
}

__global__ void k_scan2(int* __restrict__ partial, int nb) {
    __shared__ int sh[256];
    __shared__ int carry;
    int tx = threadIdx.x;
    if (tx == 0) carry = 0;
    __syncthreads();
    for (int base = 0; base < nb; base += 256) {
        int i = base + tx;
        int v = (i < nb) ? partial[i] : 0;
        int c0 = carry;
        sh[tx] = v;
        __syncthreads();
        for (int off = 1; off < 256; off <<= 1) {
            int add = (tx >= off) ? sh[tx - off] : 0;
            __syncthreads();
            sh[tx] += add;
            __syncthreads();
        }
        if (i < nb) partial[i] = c0 + sh[tx] - v;
        __syncthreads();
        if (tx == 0) carry = c0 + sh[255];
        __syncthreads();
    }
}

// ---------------- binning ----------------

__global__ void k_histA(const int* __restrict__ dst, int* __restrict__ cnt,
                        int e, int nbuck, int nblkA) {
    __shared__ int hist[NBUCK_MAX];
    int tx = threadIdx.x, blk = blockIdx.x;
    for (int b = tx; b < nbuck; b += 1024) hist[b] = 0;
    __syncthreads();
    size_t base = (size_t)blk * EPA;
    const int4v* dst4 = (const int4v*)dst;
    for (int k = 0; k < EPA / 4096; ++k) {
        size_t e4 = base / 4 + (size_t)k * 1024 + tx;
        size_t i = e4 * 4;
        if (i + 3 < (size_t)e) {
            int4v d4 = __builtin_nontemporal_load(&dst4[e4]);
#pragma unroll
            for (int j = 0; j < 4; ++j) atomicAdd(&hist[d4[j] >> 8], 1);
        } else {
            for (int j = 0; j < 4; ++j) {
                size_t ii = i + j;
                if (ii < (size_t)e) atomicAdd(&hist[dst[ii] >> 8], 1);
            }
        }
    }
    __syncthreads();
    for (int b = tx; b < nbuck; b += 1024) cnt[(size_t)b * nblkA + blk] = hist[b];
}

// LDS-staged scatter: local hist LOADED from cnt (histA already computed it),
// scan -> stage sorted-by-bucket into LDS -> coalesced run flush.
__global__ void k_scatterA(const int* __restrict__ src, const int* __restrict__ dst,
                           const int* __restrict__ cnt,
                           const int* __restrict__ scn, const int* __restrict__ part,
                           unsigned int* __restrict__ binnedA,
                           int e, int nbuck, int nblkA) {
    __shared__ int lstart[NBUCK_MAX];          // local counts -> exclusive scan
    __shared__ int cur[NBUCK_MAX];
    __shared__ int gbase[NBUCK_MAX];
    __shared__ unsigned int staged[EPA];       // 128 KB
    int tx = threadIdx.x, blk = blockIdx.x;
    for (int b = tx; b < NBUCK_MAX; b += 1024) {
        if (b < nbuck) {
            size_t idx = (size_t)b * nblkA + blk;
            lstart[b] = cnt[idx];
            gbase[b] = scn[idx] + part[idx >> 8];
        } else {
            lstart[b] = 0;
        }
    }
    __syncthreads();
    // in-place inclusive scan of lstart[2048], 2 elems/thread
    int j0 = tx, j1 = tx + 1024;
    int c0 = lstart[j0], c1 = lstart[j1];
    for (int off = 1; off < NBUCK_MAX; off <<= 1) {
        int a0 = (j0 >= off) ? lstart[j0 - off] : 0;
        int a1 = (j1 >= off) ? lstart[j1 - off] : 0;
        __syncthreads();
        lstart[j0] += a0; lstart[j1] += a1;
        __syncthreads();
    }
    int e0 = lstart[j0] - c0, e1 = lstart[j1] - c1;
    __syncthreads();
    lstart[j0] = e0; lstart[j1] = e1;
    cur[j0] = e0;    cur[j1] = e1;
    __syncthreads();
    // stage sorted-by-bucket into LDS (scattered LDS writes ~free)
    size_t base = (size_t)blk * EPA;
    const int4v* dst4 = (const int4v*)dst;
    const int4v* src4 = (const int4v*)src;
    for (int k = 0; k < EPA / 4096; ++k) {
        size_t e4 = base / 4 + (size_t)k * 1024 + tx;
        size_t i = e4 * 4;
        if (i + 3 < (size_t)e) {
            int4v d4 = __builtin_nontemporal_load(&dst4[e4]);
            int4v s4 = __builtin_nontemporal_load(&src4[e4]);
#pragma unroll
            for (int j = 0; j < 4; ++j) {
                int d = d4[j];
                int pos = atomicAdd(&cur[d >> 8], 1);
                staged[pos] = ((unsigned int)(d & (RB - 1)) << 19) | (unsigned int)s4[j];
            }
        } else {
            for (int j = 0; j < 4; ++j) {
                size_t ii = i + j;
                if (ii < (size_t)e) {
                    int d = dst[ii];
                    int pos = atomicAdd(&cur[d >> 8], 1);
                    staged[pos] = ((unsigned int)(d & (RB - 1)) << 19) | (unsigned int)src[ii];
                }
            }
        }
    }
    __syncthreads();
    // flush: 16 lanes per bucket-run -> contiguous global writes
    int grp = tx >> 4, lane = tx & 15;
    for (int b = grp; b < nbuck; b += 64) {
        int ls = lstart[b];
        int le = (b + 1 < NBUCK_MAX) ? lstart[b + 1] : 0;
        int len = le - ls;
        int gb = gbase[b];
        for (int k = lane; k < len; k += 16)
            binnedA[gb + k] = staged[ls + k];
    }
}

// ---------------- passC: PHASE-MAJOR 512-bin sort + p0ptr/p1ptr + g1 ----------------
// key = (phase<<8)|dl : bucket segment = [phase0 by node | phase1 by node].
// Register-staged: bucket edges (<= OCAP = 20*512) in 20 static VGPRs.

__global__ void k_passC(const unsigned int* __restrict__ binnedA,
                        const int* __restrict__ scn, const int* __restrict__ part,
                        const float* __restrict__ x,
                        half8* __restrict__ g1, unsigned int* __restrict__ binned3,
                        int* __restrict__ p0ptr, int* __restrict__ p1ptr,
                        int n, int e, int nbuck, int nblkA, unsigned int half) {
    __shared__ int hist[2 * RB];       // 512 bins: (phase<<8)|dl
    __shared__ int scanbuf[2 * RB];
    __shared__ int cur[2 * RB];
    __shared__ unsigned int obuf[OCAP];   // 40 KB
    int tx = threadIdx.x, b = blockIdx.x;  // blockDim 512
    hist[tx] = 0;
    __syncthreads();
    size_t i0 = (size_t)b * nblkA;
    int start = scn[i0] + part[i0 >> 8];
    int end;
    if (b + 1 < nbuck) {
        size_t i1 = (size_t)(b + 1) * nblkA;
        end = scn[i1] + part[i1 >> 8];
    } else {
        end = e;
    }
    int len = end - start;
    bool stage = (len <= OCAP);
    unsigned int r[20];
    if (stage) {
#pragma unroll
        for (int k = 0; k < 20; ++k) {
            int i = start + k * 512 + tx;
            if (i < end) {
                unsigned int p = binnedA[i];
                r[k] = p;
                int key = ((p & 0x7FFFFu) >= half ? 256 : 0) | (int)(p >> 19);
                atomicAdd(&hist[key], 1);
            }
        }
    } else {
        for (int i = start + tx; i < end; i += 512) {
            unsigned int p = binnedA[i];
            int key = ((p & 0x7FFFFu) >= half ? 256 : 0) | (int)(p >> 19);
            atomicAdd(&hist[key], 1);
        }
    }
    __syncthreads();
    int v = hist[tx];
    scanbuf[tx] = v;
    __syncthreads();
    for (int off = 1; off < 2 * RB; off <<= 1) {
        int add = (tx >= off) ? scanbuf[tx - off] : 0;
        __syncthreads();
        scanbuf[tx] += add;
        __syncthreads();
    }
    int excl = scanbuf[tx] - v;
    cur[tx] = excl;
    if (tx < 256) p0ptr[(size_t)b * RB + tx] = start + excl;
    else          p1ptr[(size_t)b * RB + (tx - 256)] = start + excl;
    if (tx < RB) {
        int node = b * RB + tx;
        if (node < n) {
            int deg = hist[tx] + hist[256 + tx];
            float d = rsqrtf((float)(deg + 1));  // +1 self-loop
            const float* xp = x + (size_t)node * FIN;
            half8 row = {};
#pragma unroll
            for (int f = 0; f < FIN; ++f) row[f] = (_Float16)(xp[f] * d);
            row[5] = (_Float16)d;                // dinv folded into slot 5
            g1[node] = row;
        }
    }
    if (b == nbuck - 1 && tx == 0) p0ptr[(size_t)nbuck * RB] = end;  // global sentinel
    __syncthreads();
    if (stage) {
#pragma unroll
        for (int k = 0; k < 20; ++k) {
            int i = start + k * 512 + tx;
            if (i < end) {
                unsigned int p = r[k];
                int key = ((p & 0x7FFFFu) >= half ? 256 : 0) | (int)(p >> 19);
                int pos = atomicAdd(&cur[key], 1);
                obuf[pos] = p & 0x7FFFFu;
            }
        }
        __syncthreads();
        for (int j = tx; j < len; j += 512)
            binned3[start + j] = obuf[j];
    } else {
        for (int i = start + tx; i < end; i += 512) {
            unsigned int p = binnedA[i];
            int key = ((p & 0x7FFFFu) >= half ? 256 : 0) | (int)(p >> 19);
            int pos = atomicAdd(&cur[key], 1);
            binned3[start + pos] = p & 0x7FFFFu;
        }
    }
}

// ---------------- aggregation: phase-split, 16 lanes/node, packed-f16 accum ----------------
// phase-0 range: [p0[node], dl==255 ? p1[bucket_first] : p0[node+1])
// phase-1 range: [p1[node], dl==255 ? p0[bucket_first+RB] : p1[node+1])

// phase 0 (src < half): gather half-table (L2-resident), store f32 partials
__global__ void k_vphase0(const unsigned int* __restrict__ ed,
                          const int* __restrict__ p0, const int* __restrict__ p1,
                          const half8* __restrict__ g,
                          fl4* __restrict__ acc4, float* __restrict__ acc1, int n) {
    int tid = blockIdx.x * blockDim.x + threadIdx.x;
    int node = tid >> 4;
    int lane = tid & 15;
    if (node >= n) return;
    int dl = node & (RB - 1);
    int o0 = p0[node];
    int oe = (dl == RB - 1) ? p1[node & ~(RB - 1)] : p0[node + 1];
    half8 acch = {};
    for (int k = o0 + lane; k < oe; k += 16) {
        unsigned int s = __builtin_nontemporal_load(&ed[k]);
        acch += g[s];                      // 4x v_pk_add_f16
    }
    acch = bfly16_h8(acch);
    if (lane == 0) {
        fl4 p; p.x = (float)acch[0]; p.y = (float)acch[1];
        p.z = (float)acch[2]; p.w = (float)acch[3];
        __builtin_nontemporal_store(p, &acc4[node]);
        __builtin_nontemporal_store((float)acch[4], &acc1[node]);
    }
}

// phase 1 layer 1 (src >= half): add partials + self, W1+relu epilogue
__global__ void k_vp1_l1(const unsigned int* __restrict__ ed,
                         const int* __restrict__ p0, const int* __restrict__ p1,
                         const half8* __restrict__ g1,
                         const fl4* __restrict__ acc4, const float* __restrict__ acc1,
                         const float* __restrict__ W1, const float* __restrict__ b1,
                         half8* __restrict__ g2, int n) {
    int tid = blockIdx.x * blockDim.x + threadIdx.x;
    int node = tid >> 4;
    int lane = tid & 15;
    if (node >= n) return;
    int dl = node & (RB - 1);
    int o0 = p1[node];
    int oe = (dl == RB - 1) ? p0[(node & ~(RB - 1)) + RB] : p1[node + 1];
    half8 acch = {};
    for (int k = o0 + lane; k < oe; k += 16) {
        unsigned int s = __builtin_nontemporal_load(&ed[k]);
        acch += g1[s];
    }
    acch = bfly16_h8(acch);
    if (lane == 0) {
        fl4 pp = acc4[node];
        float p4 = acc1[node];
        half8 gi = g1[node];
        float d = (float)gi[5];
        float v[FIN];
        v[0] = ((float)acch[0] + pp.x + (float)gi[0]) * d;
        v[1] = ((float)acch[1] + pp.y + (float)gi[1]) * d;
        v[2] = ((float)acch[2] + pp.z + (float)gi[2]) * d;
        v[3] = ((float)acch[3] + pp.w + (float)gi[3]) * d;
        v[4] = ((float)acch[4] + p4   + (float)gi[4]) * d;
        half8 go = {};
#pragma unroll
        for (int j = 0; j < FHID; ++j) {
            float s = b1[j];
#pragma unroll
            for (int k = 0; k < FIN; ++k) s = fmaf(v[k], W1[k * FHID + j], s);
            go[j] = (_Float16)(fmaxf(s, 0.0f) * d);  // relu, pre-scaled
        }
        go[5] = gi[5];
        g2[node] = go;
    }
}

// phase 1 layer 2: packed accum + parallel softmax epilogue -- lane j&7 owns
// output j&7, width-8 butterfly max/sum, lanes 0-7 store coalesced.
__global__ void k_vp1_l2(const unsigned int* __restrict__ ed,
                         const int* __restrict__ p0, const int* __restrict__ p1,
                         const half8* __restrict__ g2,
                         const fl4* __restrict__ acc4, const float* __restrict__ acc1,
                         const float* __restrict__ W2, const float* __restrict__ b2,
                         float* __restrict__ out, int n) {
    int tid = blockIdx.x * blockDim.x + threadIdx.x;
    int node = tid >> 4;
    int lane = tid & 15;
    if (node >= n) return;
    int dl = node & (RB - 1);
    int o0 = p1[node];
    int oe = (dl == RB - 1) ? p0[(node & ~(RB - 1)) + RB] : p1[node + 1];
    half8 acch = {};
    for (int k = o0 + lane; k < oe; k += 16) {
        unsigned int s = __builtin_nontemporal_load(&ed[k]);
        acch += g2[s];
    }
    acch = bfly16_h8(acch);   // all 16 lanes end with the full sums
    fl4 pp = acc4[node];
    float p4 = acc1[node];
    half8 gi = g2[node];
    float d = (float)gi[5];
    float v[FHID];
    v[0] = ((float)acch[0] + pp.x + (float)gi[0]) * d;
    v[1] = ((float)acch[1] + pp.y + (float)gi[1]) * d;
    v[2] = ((float)acch[2] + pp.z + (float)gi[2]) * d;
    v[3] = ((float)acch[3] + pp.w + (float)gi[3]) * d;
    v[4] = ((float)acch[4] + p4   + (float)gi[4]) * d;
    int j = lane & 7;                      // lane j owns output j (both halves compute)
    float oj = b2[j];
#pragma unroll
    for (int k = 0; k < FHID; ++k) oj = fmaf(v[k], W2[k * FOUT + j], oj);
    float mx = oj;
#pragma unroll
    for (int off = 1; off < 8; off <<= 1) mx = fmaxf(mx, __shfl_xor(mx, off, 8));
    float ex = expf(oj - mx);
    float ss = ex;
#pragma unroll
    for (int off = 1; off < 8; off <<= 1) ss += __shfl_xor(ss, off, 8);
    if (lane < 8) out[(size_t)node * FOUT + j] = oj - mx - logf(ss);  // coalesced
}

// ---------------- fallback (R1 atomic path) ----------------

__global__ void f_init_deg(float* __restrict__ deg, int n) {
    int i = blockIdx.x * blockDim.x + threadIdx.x;
    if (i < n) deg[i] = 1.0f;
}
__global__ void f_count_deg(const int* __restrict__ dst, float* __restrict__ deg, int e) {
    int i = blockIdx.x * blockDim.x + threadIdx.x;
    if (i < e) atomicAdd(&deg[dst[i]], 1.0f);
}
__global__ void f_finish_deg_g1(const float* __restrict__ x, float* __restrict__ dinv,
                                float* __restrict__ g1, int n) {
    int i = blockIdx.x * blockDim.x + threadIdx.x;
    if (i >= n) return;
    float d = rsqrtf(dinv[i]);
    dinv[i] = d;
#pragma unroll
    for (int f = 0; f < FIN; ++f) g1[(size_t)i * FIN + f] = x[(size_t)i * FIN + f] * d;
}
__global__ void f_scatter5(const int* __restrict__ src, const int* __restrict__ dst,
                           const float* __restrict__ g, float* __restrict__ acc, int e) {
    int i = blockIdx.x * blockDim.x + threadIdx.x;
    if (i >= e) return;
    int s = src[i], d = dst[i];
    float* a = acc + (size_t)d * 5;
    const float* gp = g + (size_t)s * 5;
    atomicAdd(a + 0, gp[0]);
    atomicAdd(a + 1, gp[1]);
    atomicAdd(a + 2, gp[2]);
    atomicAdd(a + 3, gp[3]);
    atomicAdd(a + 4, gp[4]);
}
__global__ void f_update1(const float* __restrict__ dinv, float* __restrict__ g,
                          float* __restrict__ acc, const float* __restrict__ W1,
                          const float* __restrict__ b1, int n) {
    int i = blockIdx.x * blockDim.x + threadIdx.x;
    if (i >= n) return;
    float d = dinv[i];
    float v[FIN];
#pragma unroll
    for (int f = 0; f < FIN; ++f) {
        size_t idx = (size_t)i * FIN + f;
        v[f] = (acc[idx] + g[idx]) * d;
        acc[idx] = 0.0f;
    }
#pragma unroll
    for (int j = 0; j < FHID; ++j) {
        float s = b1[j];
#pragma unroll
        for (int k = 0; k < FIN; ++k) s += v[k] * W1[k * FHID + j];
        g[(size_t)i * FHID + j] = fmaxf(s, 0.0f) * d;
    }
}
__global__ void f_update2(const float* __restrict__ dinv, const float* __restrict__ g,
                          const float* __restrict__ acc, const float* __restrict__ W2,
                          const float* __restrict__ b2, float* __restrict__ out, int n) {
    int i = blockIdx.x * blockDim.x + threadIdx.x;
    if (i >= n) return;
    float d = dinv[i];
    float v[FHID];
#pragma unroll
    for (int f = 0; f < FHID; ++f) v[f] = (acc[(size_t)i * FHID + f] + g[(size_t)i * FHID + f]) * d;
    float o[FOUT];
    float m = -1e30f;
#pragma unroll
    for (int j = 0; j < FOUT; ++j) {
        float s = b2[j];
#pragma unroll
        for (int k = 0; k < FHID; ++k) s += v[k] * W2[k * FOUT + j];
        o[j] = s;
        m = fmaxf(m, s);
    }
    float ssum = 0.0f;
#pragma unroll
    for (int j = 0; j < FOUT; ++j) ssum += expf(o[j] - m);
    float lse = m + logf(ssum);
#pragma unroll
    for (int j = 0; j < FOUT; ++j) out[(size_t)i * FOUT + j] = o[j] - lse;
}

// ---------------- launcher ----------------

extern "C" void kernel_launch(void* const* d_in, const int* in_sizes, int n_in,
                              void* d_out, int out_size, void* d_ws, size_t ws_size,
                              hipStream_t stream) {
    const float* x  = (const float*)d_in[0];
    const int*   ei = (const int*)d_in[1];
    const float* W1 = (const float*)d_in[2];
    const float* b1 = (const float*)d_in[3];
    const float* W2 = (const float*)d_in[4];
    const float* b2 = (const float*)d_in[5];

    const int n = in_sizes[0] / FIN;   // 500,000
    const int e = in_sizes[1] / 2;     // 16,000,000
    const int* src = ei;
    const int* dst = ei + e;

    const int nbuck = (n + RB - 1) / RB;          // 1954
    const int nblkA = (e + EPA - 1) / EPA;        // 489
    const size_t m = (size_t)nbuck * nblkA;       // ~955k
    const int nsb = (int)((m + 255) / 256);

    size_t off = 0;
    auto al = [&](size_t bytes) { size_t o = off; off = (off + bytes + 15) & ~(size_t)15; return o; };
    int*          cnt     = (int*)((char*)d_ws + al(m * 4));
    int*          scn     = (int*)((char*)d_ws + al(m * 4));
    int*          part    = (int*)((char*)d_ws + al((size_t)nsb * 4));
    int*          p0ptr   = (int*)((char*)d_ws + al(((size_t)nbuck * RB + 1) * 4));
    int*          p1ptr   = (int*)((char*)d_ws + al((size_t)nbuck * RB * 4));
    half8*        g1      = (half8*)((char*)d_ws + al((size_t)n * 16));
    unsigned int* binnedA = (unsigned int*)((char*)d_ws + al((size_t)e * 4));
    unsigned int* binned3 = (unsigned int*)((char*)d_ws + al((size_t)e * 4));
    // binnedA (64 MB) dead after passC -- carve post-sort buffers from it:
    half8*        g2      = (half8*)binnedA;                                     // 8 MB @ 0
    fl4*          acc4    = (fl4*)((char*)binnedA + (size_t)16 * 1024 * 1024);   // 8 MB @ 16M
    float*        acc1    = (float*)((char*)binnedA + (size_t)32 * 1024 * 1024); // 2 MB @ 32M
    const size_t need = off;

    if (ws_size >= need && n <= 524288 && n >= 1 && (e & 3) == 0 && nbuck <= NBUCK_MAX &&
        (size_t)e * 4 >= (size_t)34 * 1024 * 1024 && (size_t)n * 16 <= (size_t)16 * 1024 * 1024) {
        const unsigned int half = (unsigned int)(n >> 1);
        k_histA<<<nblkA, 1024, 0, stream>>>(dst, cnt, e, nbuck, nblkA);
        k_scan1<<<nsb, 256, 0, stream>>>(cnt, scn, part, (int)m);
        k_scan2<<<1, 256, 0, stream>>>(part, nsb);
        k_scatterA<<<nblkA, 1024, 0, stream>>>(src, dst, cnt, scn, part, binnedA, e, nbuck, nblkA);
        k_passC<<<nbuck, 512, 0, stream>>>(binnedA, scn, part, x, g1, binned3, p0ptr, p1ptr,
                                           n, e, nbuck, nblkA, half);
        const int ga = (int)(((size_t)n * 16 + 511) / 512);
        k_vphase0<<<ga, 512, 0, stream>>>(binned3, p0ptr, p1ptr, g1, acc4, acc1, n);
        k_vp1_l1<<<ga, 512, 0, stream>>>(binned3, p0ptr, p1ptr, g1, acc4, acc1, W1, b1, g2, n);
        k_vphase0<<<ga, 512, 0, stream>>>(binned3, p0ptr, p1ptr, g2, acc4, acc1, n);
        k_vp1_l2<<<ga, 512, 0, stream>>>(binned3, p0ptr, p1ptr, g2, acc4, acc1, W2, b2, (float*)d_out, n);
        return;
    }

    // R1 fallback (22 MB ws)
    const int B = 256;
    const int gn = (n + B - 1) / B;
    const int ge = (e + B - 1) / B;
    float* fdinv = (float*)d_ws;
    float* fg    = fdinv + n;
    float* facc  = fg + (size_t)5 * n;
    hipMemsetAsync(facc, 0, (size_t)5 * n * sizeof(float), stream);
    f_init_deg<<<gn, B, 0, stream>>>(fdinv, n);
    f_count_deg<<<ge, B, 0, stream>>>(dst, fdinv, e);
    f_finish_deg_g1<<<gn, B, 0, stream>>>(x, fdinv, fg, n);
    f_scatter5<<<ge, B, 0, stream>>>(src, dst, fg, facc, e);
    f_update1<<<gn, B, 0, stream>>>(fdinv, fg, facc, W1, b1, n);
    f_scatter5<<<ge, B, 0, stream>>>(src, dst, fg, facc, e);
    f_update2<<<gn, B, 0, stream>>>(fdinv, fg, facc, W2, b2, (float*)d_out, n);
}